// Round 8
// baseline (467.953 us; speedup 1.0000x reference)
//
#include <hip/hip_runtime.h>
#include <hip/hip_bf16.h>

// MLA forward, MI355X round 8: equal-duration kv-split attention.
// Pairs (qt_h=8+pi, qt_l=7-pi): half0 = qt_h kv[0,17); half1 = qt_h kv[17,..)
// then qt_l full. All 512 blocks = 17 kv-tile jobs -> sustained 2 blocks/CU.
// Heavy q-tiles merged from fp32 partials (stored in d_out, dead until proj).
// B=2 S=2048 D=2048 H=16 NOPE=128 ROPE=64 VH=128 QR=KVR=512

typedef __attribute__((ext_vector_type(8))) short s8v;   // 8 bf16 (4 VGPR)
typedef __attribute__((ext_vector_type(4))) float f4v;   // 4 fp32 acc

#define DEV static __device__ __forceinline__

DEV ushort f2b(float f) {
  __hip_bfloat16 h = __float2bfloat16(f);
  return *reinterpret_cast<ushort*>(&h);
}
DEV float b2f(ushort u) {
  __hip_bfloat16 h = *reinterpret_cast<__hip_bfloat16*>(&u);
  return __bfloat162float(h);
}
DEV f4v mfma16(s8v a, s8v b, f4v c) {
  return __builtin_amdgcn_mfma_f32_16x16x32_bf16(a, b, c, 0, 0, 0);
}
DEV void gload16(const ushort* g, ushort* l) {
  __builtin_amdgcn_global_load_lds((const __attribute__((address_space(1))) void*)g,
                                   (__attribute__((address_space(3))) void*)l, 16, 0, 0);
}
DEV void barrier_raw() {
  __builtin_amdgcn_sched_barrier(0);
  __builtin_amdgcn_s_barrier();
  __builtin_amdgcn_sched_barrier(0);
}

// ---------------------------------------------------------------- all casts, one launch
struct CastSeg { const float* src; ushort* dst; int n4; int blk0; };
struct CastTab { CastSeg seg[10]; };

__global__ __launch_bounds__(256) void cast_all_kernel(CastTab t) {
  int b = blockIdx.x;
  int si = 0;
#pragma unroll
  for (int i = 1; i < 10; ++i) si = (b >= t.seg[i].blk0) ? i : si;
  int i4 = (b - t.seg[si].blk0) * 256 + threadIdx.x;
  if (i4 >= t.seg[si].n4) return;
  ushort4 o;
  if (t.seg[si].src) {
    float4 v = reinterpret_cast<const float4*>(t.seg[si].src)[i4];
    o.x = f2b(v.x); o.y = f2b(v.y); o.z = f2b(v.z); o.w = f2b(v.w);
  } else {
    o = ushort4{0, 0, 0, 0};
  }
  reinterpret_cast<ushort4*>(t.seg[si].dst)[i4] = o;
}

// ---------------------------------------------------------------- GEMM C = A * B^T
// 128x128 tile, BK=32, global_load_lds dwordx4, double-buffered, 4 waves.
template <bool BF16OUT>
DEV void gemm_core(const ushort* __restrict__ A, const ushort* __restrict__ B,
                   void* __restrict__ C, int N, int K, int row0, int col0,
                   ushort* a_lds0, ushort* a_lds1, ushort* b_lds0, ushort* b_lds1) {
  const int tid = threadIdx.x;
  const int lane = tid & 63, wv = tid >> 6;
  const int wm = wv >> 1, wn = wv & 1;
  const int l15 = lane & 15, l4 = lane >> 4;
  const int srow = lane >> 2;
  const int scol = (lane & 3) * 8;
  ushort* a_lds[2] = {a_lds0, a_lds1};
  ushort* b_lds[2] = {b_lds0, b_lds1};

  f4v acc[4][4];
#pragma unroll
  for (int i = 0; i < 4; ++i)
#pragma unroll
    for (int j = 0; j < 4; ++j) acc[i][j] = f4v{0.f, 0.f, 0.f, 0.f};

  auto stage = [&](int k0, int bsel) {
#pragma unroll
    for (int i = 0; i < 2; ++i) {
      int s = wv * 2 + i;
      gload16(&A[(size_t)(row0 + s * 16 + srow) * K + k0 + scol], &a_lds[bsel][s * 512]);
      gload16(&B[(size_t)(col0 + s * 16 + srow) * K + k0 + scol], &b_lds[bsel][s * 512]);
    }
  };

  stage(0, 0);
  int cur = 0;
  for (int k0 = 0; k0 < K; k0 += 32) {
    __syncthreads();
    if (k0 + 32 < K) stage(k0 + 32, cur ^ 1);
    s8v af[4], bfr[4];
#pragma unroll
    for (int mi = 0; mi < 4; ++mi)
      af[mi] = *reinterpret_cast<const s8v*>(&a_lds[cur][(wm * 64 + mi * 16 + l15) * 32 + 8 * l4]);
#pragma unroll
    for (int ni = 0; ni < 4; ++ni)
      bfr[ni] = *reinterpret_cast<const s8v*>(&b_lds[cur][(wn * 64 + ni * 16 + l15) * 32 + 8 * l4]);
#pragma unroll
    for (int mi = 0; mi < 4; ++mi)
#pragma unroll
      for (int ni = 0; ni < 4; ++ni) acc[mi][ni] = mfma16(af[mi], bfr[ni], acc[mi][ni]);
    cur ^= 1;
  }

#pragma unroll
  for (int mi = 0; mi < 4; ++mi)
#pragma unroll
    for (int ni = 0; ni < 4; ++ni)
#pragma unroll
      for (int j = 0; j < 4; ++j) {
        int r = row0 + wm * 64 + mi * 16 + l4 * 4 + j;   // C/D: row=(lane>>4)*4+reg
        int cl = col0 + wn * 64 + ni * 16 + l15;          //      col=lane&15
        if (BF16OUT)
          reinterpret_cast<ushort*>(C)[(size_t)r * N + cl] = f2b(acc[mi][ni][j]);
        else
          reinterpret_cast<float*>(C)[(size_t)r * N + cl] = acc[mi][ni][j];
      }
}

template <bool BF16OUT>
__global__ __launch_bounds__(256) void gemm_bt(const ushort* __restrict__ A,
                                               const ushort* __restrict__ B,
                                               void* __restrict__ C, int N, int K) {
  __shared__ ushort a0[128 * 32], a1[128 * 32], b0[128 * 32], b1[128 * 32];
  gemm_core<BF16OUT>(A, B, C, N, K, blockIdx.x * 128, blockIdx.y * 128, a0, a1, b0, b1);
}

// Q-decompress (N=3072) and KV-decompress (N=4096) in one launch. K=512, M=4096.
__global__ __launch_bounds__(256) void gemm2_dual(const ushort* __restrict__ nq,
                                                  const ushort* __restrict__ w2q,
                                                  ushort* __restrict__ g2q,
                                                  const ushort* __restrict__ nkv,
                                                  const ushort* __restrict__ w2kv,
                                                  ushort* __restrict__ g2kv) {
  __shared__ ushort a0[128 * 32], a1[128 * 32], b0[128 * 32], b1[128 * 32];
  int by = blockIdx.y;
  if (by < 24)
    gemm_core<true>(nq, w2q, g2q, 3072, 512, blockIdx.x * 128, by * 128, a0, a1, b0, b1);
  else
    gemm_core<true>(nkv, w2kv, g2kv, 4096, 512, blockIdx.x * 128, (by - 24) * 128, a0, a1, b0, b1);
}

// ---------------------------------------------------------------- RMSNorm(cq,ckv) + RoPE(k_rope)
__global__ __launch_bounds__(256) void norm_rope1_kernel(
    const float* __restrict__ g1, const float* __restrict__ wq, const float* __restrict__ wkv,
    const float* __restrict__ freqs, ushort* __restrict__ nq, ushort* __restrict__ nkv,
    ushort* __restrict__ kro) {
  const int m = blockIdx.x;       // 0..4095 = b*2048+s
  const int s = m & 2047;
  const int tid = threadIdx.x;
  __shared__ float red[4];
  const float* row = g1 + (size_t)m * 1152;

  float v0 = row[tid], v1 = row[tid + 256];
  float ss = v0 * v0 + v1 * v1;
#pragma unroll
  for (int off = 32; off > 0; off >>= 1) ss += __shfl_down(ss, off);
  if ((tid & 63) == 0) red[tid >> 6] = ss;
  __syncthreads();
  float r = rsqrtf((red[0] + red[1] + red[2] + red[3]) * (1.0f / 512.0f) + 1e-6f);
  nq[(size_t)m * 512 + tid] = f2b(v0 * r * wq[tid]);
  nq[(size_t)m * 512 + tid + 256] = f2b(v1 * r * wq[tid + 256]);

  float u0 = row[512 + tid], u1 = row[512 + tid + 256];
  float ss2 = u0 * u0 + u1 * u1;
#pragma unroll
  for (int off = 32; off > 0; off >>= 1) ss2 += __shfl_down(ss2, off);
  __syncthreads();
  if ((tid & 63) == 0) red[tid >> 6] = ss2;
  __syncthreads();
  float r2 = rsqrtf((red[0] + red[1] + red[2] + red[3]) * (1.0f / 512.0f) + 1e-6f);
  nkv[(size_t)m * 512 + tid] = f2b(u0 * r2 * wkv[tid]);
  nkv[(size_t)m * 512 + tid + 256] = f2b(u1 * r2 * wkv[tid + 256]);

  if (tid < 32) {
    float x0 = row[1024 + 2 * tid], x1 = row[1024 + 2 * tid + 1];
    float c = freqs[s * 64 + 2 * tid], sn = freqs[s * 64 + 2 * tid + 1];
    kro[(size_t)m * 64 + 2 * tid] = f2b((x0 * c - x1 * sn) * (1.0f / 16.0f));
    kro[(size_t)m * 64 + 2 * tid + 1] = f2b((x0 * sn + x1 * c) * (1.0f / 16.0f));
  }
}

// ---------------------------------------------------------------- V transpose + Q RoPE, one launch
__global__ __launch_bounds__(256) void misc_fused_kernel(ushort* __restrict__ g2q,
                                                         const float* __restrict__ freqs,
                                                         const ushort* __restrict__ g2kv,
                                                         ushort* __restrict__ vT) {
  const int tid = threadIdx.x;
  if (blockIdx.x < 2048) {   // ---- V transpose: g2kv v-section -> vT (B,H,128,S)
    int blk = blockIdx.x;
    int bh = blk >> 6;
    int rem = blk & 63;
    int st = rem >> 1, dt = rem & 1;
    int b = bh >> 4, h = bh & 15;
    __shared__ ushort t[64][72];
#pragma unroll
    for (int it = 0; it < 2; ++it) {
      int c = tid + it * 256;
      int sl = c >> 3, cc = (c & 7) * 8;
      *reinterpret_cast<uint4*>(&t[sl][cc]) = *reinterpret_cast<const uint4*>(
          &g2kv[(size_t)(b * 2048 + st * 64 + sl) * 4096 + 2048 + h * 128 + dt * 64 + cc]);
    }
    __syncthreads();
#pragma unroll
    for (int it = 0; it < 2; ++it) {
      int c = tid + it * 256;
      int dl = c >> 3, cc = (c & 7) * 8;
      ushort tmp[8];
#pragma unroll
      for (int e = 0; e < 8; ++e) tmp[e] = t[cc + e][dl];
      *reinterpret_cast<uint4*>(&vT[(size_t)(bh * 128 + dt * 64 + dl) * 2048 + st * 64 + cc]) =
          *reinterpret_cast<uint4*>(tmp);
    }
  } else {                    // ---- RoPE on q_rope (in-place)
    int idx = (blockIdx.x - 2048) * 256 + tid;  // 4096*16*32
    int m = idx >> 9;
    int rem = idx & 511;
    int h = rem >> 5, j = rem & 31;
    int s = m & 2047;
    size_t base = (size_t)m * 3072 + 2048 + h * 64 + 2 * j;
    ushort2 pr = *reinterpret_cast<ushort2*>(&g2q[base]);
    float x0 = b2f(pr.x), x1 = b2f(pr.y);
    float c = freqs[s * 64 + 2 * j], sn = freqs[s * 64 + 2 * j + 1];
    ushort2 o;
    o.x = f2b(x0 * c - x1 * sn);
    o.y = f2b(x0 * sn + x1 * c);
    *reinterpret_cast<ushort2*>(&g2q[base]) = o;
  }
}

// ---------------------------------------------------------------- causal flash attention, kv-split
// 512 blocks, all EXACTLY 17 kv-tile jobs: g -> (pi=g>>6, half=(g>>5)&1, bh=g&31).
// half0: q-tile 8+pi, kv [0,17) -> partial 0. half1: q-tile 8+pi, kv [17,2qt+2)
// -> partial 1, then q-tile 7-pi full -> final. Partials (O fp32 + m,l) merged
// by merge_kernel. Swapped QK^T (P lane-local), K+V LDS dbuf (80KB, 2 blk/CU),
// one barrier + vmcnt(0) per iteration (all loads covered by a full iter).
#define MINIT -3.0e4f
__global__ __launch_bounds__(512, 4) void attn_kernel(const ushort* __restrict__ q,     // 4096x3072
                                                      const ushort* __restrict__ knope, // 4096x4096
                                                      const ushort* __restrict__ kro,   // 4096x64
                                                      const ushort* __restrict__ vT,    // (B*H*128)x2048
                                                      ushort* __restrict__ out,         // att 4096x2048
                                                      float* __restrict__ opart,        // 512x16384 (d_out)
                                                      float* __restrict__ mlbuf) {      // 512x256
  const int g = blockIdx.x;                 // 512 blocks
  const int pi = g >> 6;                    // 0..7
  const int half = (g >> 5) & 1;
  const int bh = g & 31;                    // XCD g%8 sees 4 distinct heads (L2-resident)
  const int qt_h = 8 + pi, qt_l = 7 - pi;
  const int b = bh >> 4, h = bh & 15;
  const int tid = threadIdx.x, lane = tid & 63, w = tid >> 6;
  const int l15 = lane & 15, l4 = lane >> 4;

  __shared__ ushort kbuf[2][64 * 192];      // 48KB dbuf, linear, XOR-swizzled
  __shared__ ushort vbuf[2][128 * 64];      // 32KB dbuf, linear, XOR-swizzled

  const int n1 = half ? (2 * qt_h - 15) : 17;   // jobs in segment A
  const int kvA0 = half ? 17 : 0;
  const int NJ = 17;

  auto jobQt = [&](int i) { return (i < n1) ? qt_h : qt_l; };
  auto jobKv = [&](int i) { return (i < n1) ? (kvA0 + i) : (i - n1); };

  s8v qf[6];
  auto loadQ = [&](int qt) {
    const size_t qbase = (size_t)(b * 2048 + qt * 128 + w * 16 + l15) * 3072;
#pragma unroll
    for (int kc = 0; kc < 4; ++kc)
      qf[kc] = *reinterpret_cast<const s8v*>(&q[qbase + h * 128 + kc * 32 + 8 * l4]);
#pragma unroll
    for (int kc = 4; kc < 6; ++kc)
      qf[kc] = *reinterpret_cast<const s8v*>(&q[qbase + 2048 + h * 64 + (kc - 4) * 32 + 8 * l4]);
  };

  f4v oacc[8];                              // oacc[nv][j] = O[q=w*16+4*l4+j][d=nv*16+l15]
  float m_r, l_r;                           // state for q = w*16 + l15
  auto resetS = [&]() {
#pragma unroll
    for (int i = 0; i < 8; ++i) oacc[i] = f4v{0.f, 0.f, 0.f, 0.f};
    m_r = MINIT; l_r = 0.f;
  };

  const float sc2 = 0.07216878364870323f * 1.44269504f;  // 1/sqrt(192)*log2(e)
  const int kbase = b * 2048;

  auto stageK = [&](int kv, int bsel) {
    const int krow0 = kbase + kv * 64;
#pragma unroll
    for (int i = 0; i < 3; ++i) {           // 24 segs of 1KB, 3 per wave
      int s = w * 3 + i;
      int pp = s * 1024 + lane * 16;
      int row = pp / 384;
      int col = ((pp ^ ((row & 7) << 4)) - row * 384) >> 1;
      const ushort* src = (col < 128)
          ? &knope[(size_t)(krow0 + row) * 4096 + h * 128 + col]
          : &kro[(size_t)(krow0 + row) * 64 + (col - 128)];
      gload16(src, &kbuf[bsel][s * 512]);
    }
  };
  auto stageV = [&](int kv, int bsel) {
#pragma unroll
    for (int i = 0; i < 2; ++i) {           // 16 segs of 1KB, 2 per wave
      int s = w * 2 + i;
      int pp = s * 1024 + lane * 16;
      int d = pp >> 7;
      int key = ((pp ^ ((d & 7) << 4)) & 127) >> 1;
      gload16(&vT[(size_t)(bh * 128 + d) * 2048 + kv * 64 + key], &vbuf[bsel][s * 512]);
    }
  };

  auto writePartial = [&](int part) {
    float* Op = opart + (((size_t)(pi * 32 + bh) * 2 + part) << 14);
#pragma unroll
    for (int j = 0; j < 4; ++j)
#pragma unroll
      for (int nv = 0; nv < 8; ++nv)
        Op[(w * 16 + 4 * l4 + j) * 128 + nv * 16 + l15] = oacc[nv][j];
    if (l4 == 0) {
      float* mlp = mlbuf + ((pi * 32 + bh) * 2 + part) * 256 + (w * 16 + l15) * 2;
      mlp[0] = m_r; mlp[1] = l_r;
    }
  };
  auto writeFinal = [&](int qt) {
    float invl = 1.0f / l_r;
    float invj[4];
#pragma unroll
    for (int j = 0; j < 4; ++j) invj[j] = __shfl(invl, 4 * l4 + j);
#pragma unroll
    for (int j = 0; j < 4; ++j) {
      int m = b * 2048 + qt * 128 + w * 16 + 4 * l4 + j;
#pragma unroll
      for (int nv = 0; nv < 8; ++nv)
        out[(size_t)m * 2048 + h * 128 + nv * 16 + l15] = f2b(oacc[nv][j] * invj[j]);
    }
  };

  // prologue
  loadQ(jobQt(0));
  resetS();
  stageK(jobKv(0), 0);
  stageV(jobKv(0), 0);

  for (int i = 0; i < NJ; ++i) {
    asm volatile("s_waitcnt vmcnt(0)" ::: "memory");  // job i landed; prior buf reads done
    barrier_raw();
    if (i + 1 < NJ) {                       // prefetch job i+1 (full-iter latency cover)
      stageV(jobKv(i + 1), (i + 1) & 1);
      stageK(jobKv(i + 1), (i + 1) & 1);
    }
    if (half && i == n1) {                  // segment boundary: flush heavy partial
      writePartial(1);
      resetS();
      loadQ(qt_l);
    }
    const int qt = jobQt(i), kv = jobKv(i);
    const int myq = qt * 128 + w * 16 + l15;
    const char* kb = (const char*)kbuf[i & 1];
    const char* vb = (const char*)vbuf[i & 1];

    // swapped QK^T: sacc[nb][j] = S[q=l15-owned][key=nb*16+4*l4+j]
    f4v sacc[4];
    __builtin_amdgcn_s_setprio(1);
#pragma unroll
    for (int nb = 0; nb < 4; ++nb) {
      sacc[nb] = f4v{0.f, 0.f, 0.f, 0.f};
      const int row = nb * 16 + l15;
      const int sw = (row & 7) << 4;
#pragma unroll
      for (int kc = 0; kc < 6; ++kc) {
        s8v kf = *reinterpret_cast<const s8v*>(kb + row * 384 + ((kc * 64 + l4 * 16) ^ sw));
        sacc[nb] = mfma16(kf, qf[kc], sacc[nb]);
      }
    }
    __builtin_amdgcn_s_setprio(0);

    // scale (exp2 space) + causal mask
#pragma unroll
    for (int nb = 0; nb < 4; ++nb) {
      int key = kv * 64 + nb * 16 + 4 * l4;
#pragma unroll
      for (int j = 0; j < 4; ++j) {
        float sv = sacc[nb][j] * sc2;
        if (kv >= 2 * qt && key + j > myq) sv = -INFINITY;
        sacc[nb][j] = sv;
      }
    }
    // row max (16 in-lane + shfl_xor 16,32)
    float mx = sacc[0][0];
#pragma unroll
    for (int nb = 0; nb < 4; ++nb)
#pragma unroll
      for (int j = 0; j < 4; ++j) mx = fmaxf(mx, sacc[nb][j]);
    mx = fmaxf(mx, __shfl_xor(mx, 16));
    mx = fmaxf(mx, __shfl_xor(mx, 32));

    // T13 defer-max
    if (!__all(mx - m_r <= 8.0f)) {
      float mnew = fmaxf(m_r, mx);
      float al = exp2f(m_r - mnew);
      m_r = mnew;
      l_r *= al;
      float alj[4];
#pragma unroll
      for (int j = 0; j < 4; ++j) alj[j] = __shfl(al, 4 * l4 + j);
#pragma unroll
      for (int nv = 0; nv < 8; ++nv)
#pragma unroll
        for (int j = 0; j < 4; ++j) oacc[nv][j] *= alj[j];
    }
    // P = exp2(s - m), row-sum
    float rs = 0.f;
#pragma unroll
    for (int nb = 0; nb < 4; ++nb)
#pragma unroll
      for (int j = 0; j < 4; ++j) {
        float pv = exp2f(sacc[nb][j] - m_r);
        sacc[nb][j] = pv;
        rs += pv;
      }
    rs += __shfl_xor(rs, 16);
    rs += __shfl_xor(rs, 32);
    l_r += rs;

    // P -> PV A-fragments in-register (shfl transpose)
    uint pkE[4], pkO[4];
#pragma unroll
    for (int nb = 0; nb < 4; ++nb) {
      pkE[nb] = ((uint)f2b(sacc[nb][1]) << 16) | f2b(sacc[nb][0]);
      pkO[nb] = ((uint)f2b(sacc[nb][3]) << 16) | f2b(sacc[nb][2]);
    }
    const int hi2 = l4 >> 1;
    const int sbase = l15 + 16 * (2 * (l4 & 1));
    union PF { uint u[4]; s8v v; } pf0, pf1;
#pragma unroll
    for (int t = 0; t < 4; ++t) {
      int src = sbase + 16 * (t >> 1);
      uint wa0 = __shfl((t & 1) ? pkO[0] : pkE[0], src);
      uint wb0 = __shfl((t & 1) ? pkO[1] : pkE[1], src);
      pf0.u[t] = hi2 ? wb0 : wa0;
      uint wa1 = __shfl((t & 1) ? pkO[2] : pkE[2], src);
      uint wb1 = __shfl((t & 1) ? pkO[3] : pkE[3], src);
      pf1.u[t] = hi2 ? wb1 : wa1;
    }

    // O += P V (vbuf staged one full iter ago; no mid barrier needed)
    __builtin_amdgcn_s_setprio(1);
#pragma unroll
    for (int kc2 = 0; kc2 < 2; ++kc2) {
      s8v pfr = kc2 ? pf1.v : pf0.v;
#pragma unroll
      for (int nv = 0; nv < 8; ++nv) {
        const int d = nv * 16 + l15;
        s8v vf = *reinterpret_cast<const s8v*>(vb + d * 128 + ((kc2 * 64 + l4 * 16) ^ ((d & 7) << 4)));
        oacc[nv] = mfma16(pfr, vf, oacc[nv]);
      }
    }
    __builtin_amdgcn_s_setprio(0);
  }

  if (half == 0) writePartial(0);
  else writeFinal(qt_l);
}

// ---------------------------------------------------------------- merge heavy-qtile partials
__global__ __launch_bounds__(256) void merge_kernel(const float* __restrict__ opart,
                                                    const float* __restrict__ mlbuf,
                                                    ushort* __restrict__ att) {
  const int g = blockIdx.x;                 // 256 = 8 pi x 32 bh
  const int pi = g >> 5, bh = g & 31;
  const int qt = 8 + pi, b = bh >> 4, h = bh & 15;
  const int t = threadIdx.x;
  const int r = t >> 1, c0 = (t & 1) * 64;  // row 0..127, col half

  const int pb = (pi * 32 + bh) * 2;
  float m0 = mlbuf[pb * 256 + r * 2], l0 = mlbuf[pb * 256 + r * 2 + 1];
  float m1 = mlbuf[(pb + 1) * 256 + r * 2], l1 = mlbuf[(pb + 1) * 256 + r * 2 + 1];
  float m = fmaxf(m0, m1);
  float a0 = exp2f(m0 - m), a1 = exp2f(m1 - m);
  float inv = 1.0f / (l0 * a0 + l1 * a1);

  const float* O0 = opart + ((size_t)pb << 14) + r * 128 + c0;
  const float* O1 = opart + ((size_t)(pb + 1) << 14) + r * 128 + c0;
  ushort* dst = att + (size_t)(b * 2048 + qt * 128 + r) * 2048 + h * 128 + c0;
#pragma unroll
  for (int d = 0; d < 64; d += 4) {
    float4 v0 = *reinterpret_cast<const float4*>(O0 + d);
    float4 v1 = *reinterpret_cast<const float4*>(O1 + d);
    ushort4 o;
    o.x = f2b((v0.x * a0 + v1.x * a1) * inv);
    o.y = f2b((v0.y * a0 + v1.y * a1) * inv);
    o.z = f2b((v0.z * a0 + v1.z * a1) * inv);
    o.w = f2b((v0.w * a0 + v1.w * a1) * inv);
    *reinterpret_cast<ushort4*>(dst + d) = o;
  }
}

// ---------------------------------------------------------------- launch
// Workspace layout (lifetime-aliased, peak ~97.5 MiB):
//   [ 0,32M)  g2kv   overlay: g1 fp32 18M
//   [32,56M)  g2q    overlay: xbf 16M @32M, w1 4.5M @48M
//   [56,72M)  vT     overlay: nq 4M @56M, nkv 4M @60M, w2q 3M @64M, w2kv 4M @67M
//   [72,88M)  att
//   [88,96M)  wpj
//   [96,96.5M) kro   [97,97.5M) mlbuf
// Attention O-partials (32MB fp32) live in d_out (dead until proj overwrites it).
extern "C" void kernel_launch(void* const* d_in, const int* in_sizes, int n_in,
                              void* d_out, int out_size, void* d_ws, size_t ws_size,
                              hipStream_t stream) {
  const float* x       = (const float*)d_in[0];
  const float* freqs   = (const float*)d_in[2];
  const float* w_cq    = (const float*)d_in[3];
  const float* w_qnorm = (const float*)d_in[4];
  const float* w_dqn   = (const float*)d_in[5];
  const float* w_dqr   = (const float*)d_in[6];
  const float* w_ckv   = (const float*)d_in[7];
  const float* w_kvnorm= (const float*)d_in[8];
  const float* w_dkn   = (const float*)d_in[9];
  const float* w_dv    = (const float*)d_in[10];
  const float* w_krope = (const float*)d_in[11];
  const float* w_proj  = (const float*)d_in[12];
  float* out = (float*)d_out;

  char* ws = (char*)d_ws;
  const size_t MB = 1ull << 20;
  ushort* g2kv = (ushort*)(ws + 0);
  float*  g1   = (float*) (ws + 0);
  ushort* g2q  = (ushort*)(ws + 32 * MB);
  ushort* xbf  = (ushort*)(ws + 32 * MB);
  ushort* w1   = (ushort*)(ws + 48 * MB);
  ushort* vT   = (ushort*)(ws + 56 * MB);
  ushort* nq   = (ushort*)(ws + 56 * MB);
  ushort* nkv  = (ushort*)(ws + 60 * MB);
  ushort* w2q  = (ushort*)(ws + 64 * MB);
  ushort* w2kv = (ushort*)(ws + 67 * MB);
  ushort* att  = (ushort*)(ws + 72 * MB);
  ushort* wpj  = (ushort*)(ws + 88 * MB);
  ushort* kro  = (ushort*)(ws + 96 * MB);
  float*  mlb  = (float*) (ws + 97 * MB);
  float*  opart= out;                       // 32MB partials in d_out

  // one cast launch for everything (src=nullptr => zero-fill)
  CastTab t;
  const float* srcs[10] = {x, w_cq, w_ckv, w_krope, nullptr,
                           w_dqn, w_dqr, w_dkn, w_dv, w_proj};
  ushort* dsts[10] = {xbf, w1, w1 + 512 * 2048, w1 + 1024 * 2048, w1 + 1088 * 2048,
                      w2q, w2q + 2048 * 512, w2kv, w2kv + 2048 * 512, wpj};
  int ns[10] = {4096 * 2048, 512 * 2048, 512 * 2048, 64 * 2048, 64 * 2048,
                2048 * 512, 1024 * 512, 2048 * 512, 2048 * 512, 2048 * 2048};
  int blk = 0;
  for (int i = 0; i < 10; ++i) {
    t.seg[i].src = srcs[i];
    t.seg[i].dst = dsts[i];
    t.seg[i].n4 = ns[i] / 4;
    t.seg[i].blk0 = blk;
    blk += (ns[i] / 4 + 255) / 256;
  }
  cast_all_kernel<<<blk, 256, 0, stream>>>(t);

  // fused compress GEMM  [cq | ckv | krope]
  gemm_bt<false><<<dim3(32, 9), 256, 0, stream>>>(xbf, w1, g1, 1152, 2048);
  // RMSNorm + k_rope RoPE
  norm_rope1_kernel<<<4096, 256, 0, stream>>>(g1, w_qnorm, w_kvnorm, freqs, nq, nkv, kro);
  // Q + KV decompress, one launch
  gemm2_dual<<<dim3(32, 56), 256, 0, stream>>>(nq, w2q, g2q, nkv, w2kv, g2kv);
  // V transpose + Q RoPE, one launch
  misc_fused_kernel<<<2048 + 8192, 256, 0, stream>>>(g2q, freqs, g2kv, vT);
  // causal flash attention (kv-split, equal-duration blocks)
  attn_kernel<<<512, 512, 0, stream>>>(g2q, g2kv, kro, vT, att, opart, mlb);
  // merge heavy-qtile partials into att
  merge_kernel<<<256, 256, 0, stream>>>(opart, mlb, att);
  // output projection
  gemm_bt<false><<<dim3(32, 16), 256, 0, stream>>>(att, wpj, out, 2048, 2048);
}